// Round 13
// baseline (197.705 us; speedup 1.0000x reference)
//
#include <hip/hip_runtime.h>
#include <hip/hip_fp16.h>

#define N_NODES 100000
#define N_EDGES 1600000
#define N_GRAPHS 2000
#define HID 64
#define NB 391          // final buckets of 256 nodes
#define CAP 5120        // per-bucket capacity (mean 4096; +16 sigma)
#define NSUP 16         // super-buckets of SUPW nodes
#define SUPW 6400       // 25 * 256
#define CAP_S 106496    // per-super capacity (mean 102400, +13 sigma), = 26*4096
#define CH_A 2048
#define NCH_A ((N_EDGES + CH_A - 1) / CH_A)   // 782
#define BCH 4096
#define NCHB 26         // CAP_S / BCH
#define GATHER_GRID 2048
#define NPW 13          // nodes per wave: 2048*4*13 = 106496 >= N_NODES
#define GEMM_GRID 512
#define N_TILE16 (N_NODES / 16)  // 6250 (exact)

typedef _Float16 half8 __attribute__((ext_vector_type(8)));
typedef float f32x4 __attribute__((ext_vector_type(4)));

// ---------------- utility: zero two ranges in one launch ----------------
__global__ __launch_bounds__(256) void k_zero2(int* __restrict__ p1, int n1,
                                               int* __restrict__ p2, int n2) {
    int i = blockIdx.x * 256 + threadIdx.x;
    if (i < n1) p1[i] = 0;
    if (i < n2) p2[i] = 0;
}

// ---------------- pass A: 16-way super-bucket split (dst u32 entries, src u16 entries) --------
__global__ __launch_bounds__(256) void k_passA(const int* __restrict__ src, const int* __restrict__ dst,
                                               int* __restrict__ scur_dst, int* __restrict__ scur_src,
                                               unsigned* __restrict__ sup_dst,
                                               unsigned short* __restrict__ sup_src) {
    __shared__ unsigned stD[CH_A];
    __shared__ unsigned short stS[CH_A];
    __shared__ unsigned char binD[CH_A];
    __shared__ unsigned char binS[CH_A];
    __shared__ int lcntD[NSUP], lexD[NSUP], lofD[NSUP], runD[NSUP];
    __shared__ int lcntS[NSUP], lexS[NSUP], lofS[NSUP], runS[NSUP];
    int tid = threadIdx.x;
    int e0 = blockIdx.x * CH_A;
    int n = min(CH_A, N_EDGES - e0);
    if (tid < NSUP) { lcntD[tid] = 0; lcntS[tid] = 0; }
    __syncthreads();
    int sv[8], dv[8];
#pragma unroll
    for (int k = 0; k < 8; ++k) {
        int i = k * 256 + tid;
        if (i < n) { sv[k] = src[e0 + i]; dv[k] = dst[e0 + i]; }
        else dv[k] = -1;
    }
#pragma unroll
    for (int k = 0; k < 8; ++k)
        if (dv[k] >= 0) {
            atomicAdd(&lcntD[dv[k] / SUPW], 1);
            atomicAdd(&lcntS[sv[k] / SUPW], 1);
        }
    __syncthreads();
    if (tid == 0)  { int a = 0; for (int i = 0; i < NSUP; ++i) { lexD[i] = a; lofD[i] = a; a += lcntD[i]; } }
    if (tid == 64) { int a = 0; for (int i = 0; i < NSUP; ++i) { lexS[i] = a; lofS[i] = a; a += lcntS[i]; } }
    __syncthreads();
#pragma unroll
    for (int k = 0; k < 8; ++k)
        if (dv[k] >= 0) {
            int d = dv[k], s = sv[k];
            int bD = d / SUPW;
            int pD = atomicAdd(&lofD[bD], 1);
            stD[pD] = ((unsigned)(d - bD * SUPW) << 17) | (unsigned)s;
            binD[pD] = (unsigned char)bD;
            int bS = s / SUPW;
            int pS = atomicAdd(&lofS[bS], 1);
            stS[pS] = (unsigned short)(s - bS * SUPW);
            binS[pS] = (unsigned char)bS;
        }
    __syncthreads();
    if (tid < NSUP) runD[tid] = lcntD[tid] ? atomicAdd(&scur_dst[tid], lcntD[tid]) : 0;
    if (tid >= 128 && tid < 128 + NSUP) {
        int b = tid - 128;
        runS[b] = lcntS[b] ? atomicAdd(&scur_src[b], lcntS[b]) : 0;
    }
    __syncthreads();
    for (int i = tid; i < n; i += 256) {
        int b = binD[i];
        int pos = runD[b] + (i - lexD[b]);
        if (pos < CAP_S) sup_dst[(size_t)b * CAP_S + pos] = stD[i];
    }
    for (int i = tid; i < n; i += 256) {
        int b = binS[i];
        int pos = runS[b] + (i - lexS[b]);
        if (pos < CAP_S) sup_src[(size_t)b * CAP_S + pos] = stS[i];
    }
}

// ---------------- pass B: refine each super-bucket into its 25 sub-buckets ----------------
__global__ __launch_bounds__(256) void k_passB(const unsigned* __restrict__ sup_dst,
                                               const unsigned short* __restrict__ sup_src,
                                               const int* __restrict__ scur_dst,
                                               const int* __restrict__ scur_src,
                                               int* __restrict__ gcur_dst, int* __restrict__ gcur_src,
                                               unsigned* __restrict__ part_dst,
                                               unsigned char* __restrict__ part_src) {
    __shared__ unsigned st[BCH];
    __shared__ unsigned char bin[BCH];
    __shared__ int lcnt[25], lex[25], lof[25], run[25];
    int tid = threadIdx.x;
    int isSrc = blockIdx.x >= NSUP * NCHB;
    int bx = isSrc ? blockIdx.x - NSUP * NCHB : blockIdx.x;
    int sb = bx / NCHB, ch = bx % NCHB;
    int total = isSrc ? scur_src[sb] : scur_dst[sb];
    total = min(total, CAP_S);
    int o0 = ch * BCH;
    int n = min(BCH, total - o0);
    if (n <= 0) return;
    int bg0 = sb * 25;
    if (tid < 25) lcnt[tid] = 0;
    __syncthreads();

    if (!isSrc) {
        unsigned ev[16];
        int bb[16];
#pragma unroll
        for (int k = 0; k < 16; ++k) {
            int i = k * 256 + tid;
            if (i < n) {
                unsigned e = sup_dst[(size_t)sb * CAP_S + o0 + i];
                ev[k] = e;
                bb[k] = (int)(e >> 25);
                atomicAdd(&lcnt[bb[k]], 1);
            } else bb[k] = -1;
        }
        __syncthreads();
        if (tid == 0) { int a = 0; for (int i = 0; i < 25; ++i) { lex[i] = a; lof[i] = a; a += lcnt[i]; } }
        __syncthreads();
#pragma unroll
        for (int k = 0; k < 16; ++k)
            if (bb[k] >= 0) {
                unsigned e = ev[k];
                unsigned s = e & 0x1FFFFu;
                unsigned low = (e >> 17) & 255u;
                int p = atomicAdd(&lof[bb[k]], 1);
                st[p] = (s << 8) | low;
                bin[p] = (unsigned char)bb[k];
            }
        __syncthreads();
        if (tid < 25) run[tid] = lcnt[tid] ? atomicAdd(&gcur_dst[bg0 + tid], lcnt[tid]) : 0;
        __syncthreads();
        for (int i = tid; i < n; i += 256) {
            int b = bin[i];
            int pos = run[b] + (i - lex[b]);
            if (pos < CAP) part_dst[(size_t)(bg0 + b) * CAP + pos] = st[i];
        }
    } else {
        unsigned char* st8 = (unsigned char*)st;
        int rv[16];
        int bb[16];
#pragma unroll
        for (int k = 0; k < 16; ++k) {
            int i = k * 256 + tid;
            if (i < n) {
                int r = (int)sup_src[(size_t)sb * CAP_S + o0 + i];
                rv[k] = r;
                bb[k] = r >> 8;
                atomicAdd(&lcnt[bb[k]], 1);
            } else bb[k] = -1;
        }
        __syncthreads();
        if (tid == 0) { int a = 0; for (int i = 0; i < 25; ++i) { lex[i] = a; lof[i] = a; a += lcnt[i]; } }
        __syncthreads();
#pragma unroll
        for (int k = 0; k < 16; ++k)
            if (bb[k] >= 0) {
                int p = atomicAdd(&lof[bb[k]], 1);
                st8[p] = (unsigned char)(rv[k] & 255);
                bin[p] = (unsigned char)bb[k];
            }
        __syncthreads();
        if (tid < 25) run[tid] = lcnt[tid] ? atomicAdd(&gcur_src[bg0 + tid], lcnt[tid]) : 0;
        __syncthreads();
        for (int i = tid; i < n; i += 256) {
            int b = bin[i];
            int pos = run[b] + (i - lex[b]);
            if (pos < CAP) part_src[(size_t)(bg0 + b) * CAP + pos] = st8[i];
        }
    }
}

// ---------------- merged: blocks [0,NB) build dst CSR; [NB,2NB) count out-deg -> odi ----------
__global__ __launch_bounds__(256) void k_csr_count(const unsigned* __restrict__ part_dst,
                                                   const unsigned char* __restrict__ part_src,
                                                   const int* __restrict__ gcur_dst,
                                                   const int* __restrict__ gcur_src,
                                                   int* __restrict__ rowbeg, int* __restrict__ rowend,
                                                   float* __restrict__ idi, float* __restrict__ odi,
                                                   int* __restrict__ col) {
    __shared__ int cnt[256];
    __shared__ int cur[256];
    __shared__ int wsum[4];
    int tid = threadIdx.x;
    if (blockIdx.x >= NB) {
        int b = blockIdx.x - NB;
        int nE = min(gcur_src[b], CAP);
        const unsigned char* pb = part_src + (size_t)b * CAP;
        cnt[tid] = 0;
        __syncthreads();
        for (int i = tid; i < nE; i += 256) atomicAdd(&cnt[pb[i]], 1);
        __syncthreads();
        int v = b * 256 + tid;
        if (v < N_NODES) odi[v] = rsqrtf((float)max(cnt[tid], 1));
        return;
    }
    int b = blockIdx.x;
    int base = b * CAP;
    int nE = min(gcur_dst[b], CAP);
    const unsigned* pb = part_dst + (size_t)b * CAP;
    cnt[tid] = 0;
    __syncthreads();
    for (int i = tid; i < nE; i += 256) atomicAdd(&cnt[pb[i] & 255], 1);
    __syncthreads();
    int c = cnt[tid];
    int incl = c;
#pragma unroll
    for (int off = 1; off < 64; off <<= 1) {
        int t = __shfl_up(incl, off, 64);
        if ((tid & 63) >= off) incl += t;
    }
    if ((tid & 63) == 63) wsum[tid >> 6] = incl;
    __syncthreads();
    int add = 0;
    for (int w = 0; w < (tid >> 6); ++w) add += wsum[w];
    incl += add;
    int excl = incl - c;
    int v = b * 256 + tid;
    if (v < N_NODES) {
        rowbeg[v] = base + excl;
        rowend[v] = base + incl;
        idi[v] = rsqrtf((float)max(c, 1));
    }
    cur[tid] = excl;
    __syncthreads();
    for (int i = tid; i < nE; i += 256) {
        unsigned e = pb[i];
        int p = atomicAdd(&cur[e & 255], 1);
        col[base + p] = (int)(e >> 8);
    }
}

// ---------------- dense GEMM via MFMA: zs[v] = (x[v] @ W) * odi[v]  (fp16 out) ----------------
template <int F32IN>
__global__ __launch_bounds__(256) void k_gemm_mfma(const void* __restrict__ inv,
                                                   const float* __restrict__ W,
                                                   const float* __restrict__ odi,
                                                   __half* __restrict__ zs) {
    __shared__ _Float16 Wt[64 * 64];  // Wt[j][k] = W[k][j]
    int tid = threadIdx.x;
    for (int i = tid; i < 4096; i += 256) {
        int k = i >> 6, j = i & 63;
        Wt[j * 64 + k] = (_Float16)W[i];
    }
    __syncthreads();

    int lane = tid & 63;
    int wid = tid >> 6;
    int lrow = lane & 15;
    int lgrp = lane >> 4;

    half8 Bf[4][2];
#pragma unroll
    for (int nt = 0; nt < 4; ++nt)
#pragma unroll
        for (int kh = 0; kh < 2; ++kh)
            Bf[nt][kh] = *(half8*)&Wt[(nt * 16 + lrow) * 64 + kh * 32 + lgrp * 8];

    for (int t = blockIdx.x * 4 + wid; t < N_TILE16; t += GEMM_GRID * 4) {
        int v0 = t * 16;
        half8 a0, a1;
        if (F32IN) {
            const float* A = (const float*)inv + (size_t)(v0 + lrow) * 64 + lgrp * 8;
            float4 f0 = *(const float4*)A;
            float4 f1 = *(const float4*)(A + 4);
            float4 g0 = *(const float4*)(A + 32);
            float4 g1 = *(const float4*)(A + 36);
            a0[0] = (_Float16)f0.x; a0[1] = (_Float16)f0.y; a0[2] = (_Float16)f0.z; a0[3] = (_Float16)f0.w;
            a0[4] = (_Float16)f1.x; a0[5] = (_Float16)f1.y; a0[6] = (_Float16)f1.z; a0[7] = (_Float16)f1.w;
            a1[0] = (_Float16)g0.x; a1[1] = (_Float16)g0.y; a1[2] = (_Float16)g0.z; a1[3] = (_Float16)g0.w;
            a1[4] = (_Float16)g1.x; a1[5] = (_Float16)g1.y; a1[6] = (_Float16)g1.z; a1[7] = (_Float16)g1.w;
        } else {
            const _Float16* A = (const _Float16*)inv + (size_t)(v0 + lrow) * 64 + lgrp * 8;
            a0 = *(const half8*)A;
            a1 = *(const half8*)(A + 32);
        }
        f32x4 acc[4];
#pragma unroll
        for (int nt = 0; nt < 4; ++nt) { acc[nt] = (f32x4)0.f; }
#pragma unroll
        for (int nt = 0; nt < 4; ++nt) {
            acc[nt] = __builtin_amdgcn_mfma_f32_16x16x32_f16(a0, Bf[nt][0], acc[nt], 0, 0, 0);
            acc[nt] = __builtin_amdgcn_mfma_f32_16x16x32_f16(a1, Bf[nt][1], acc[nt], 0, 0, 0);
        }
#pragma unroll
        for (int r = 0; r < 4; ++r) {
            int node = v0 + lgrp * 4 + r;
            float w = odi[node];
#pragma unroll
            for (int nt = 0; nt < 4; ++nt)
                zs[(size_t)node * 64 + nt * 16 + lrow] = __float2half_rn(acc[nt][r] * w);
        }
    }
}

// ---------------- gather v5: cross-node col prefetch pipeline ----------------
// lane = (edge-parity half, feature-pair fp). Per node: one coalesced col load (prefetched one
// node ahead so it overlaps the previous node's zs loads) + shfl-distributed srcs.
template <int RELU, int LAST>
__global__ __launch_bounds__(256) void k_gather(const __half* __restrict__ zs, const int* __restrict__ rowbeg,
                                                const int* __restrict__ rowend, const int* __restrict__ col,
                                                const float* __restrict__ idi, const float* __restrict__ b,
                                                __half* __restrict__ xout, const int* __restrict__ gid,
                                                float* __restrict__ out, float* __restrict__ partials) {
    __shared__ float part[4];
    int tid = threadIdx.x;
    int lane = tid & 63;
    int wid = tid >> 6;
    int half = lane >> 5;   // 0: even edge slot, 1: odd edge slot
    int fp = lane & 31;     // feature-pair
    float2 bias2 = *(const float2*)&b[fp * 2];
    float nacc = 0.f;
    float2 pacc = {0.f, 0.f};
    int curg = -1;

    int w = __builtin_amdgcn_readfirstlane(blockIdx.x * 4 + wid);
    int v0 = w * NPW;
    int vend = min(v0 + NPW, N_NODES);
    if (v0 >= vend) {
        if (LAST) {
            if (lane == 0) part[wid] = 0.f;
            __syncthreads();
            if (tid == 0) partials[blockIdx.x] = part[0] + part[1] + part[2] + part[3];
        }
        return;
    }

    // prologue: load node v0's descriptors + col vector
    int beg = rowbeg[v0], end = rowend[v0];
    int c = col[beg + min(lane, max(min(end - beg, 64) - 1, 0))];

    for (int v = v0; v < vend; ++v) {
        int deg = end - beg;
        int degS = min(deg, 64);
        // ---- prefetch next node's descriptors + col (overlaps this node's zs loads) ----
        int nbeg = 0, nend = 0, cn = 0;
        if (v + 1 < vend) {
            nbeg = rowbeg[v + 1];
            nend = rowend[v + 1];
            cn = col[nbeg + min(lane, max(min(nend - nbeg, 64) - 1, 0))];
        }
        float2 a0 = {0.f, 0.f}, a1 = {0.f, 0.f}, a2 = {0.f, 0.f}, a3 = {0.f, 0.f};
        int m = 0;  // pair-slot index; slot m covers edges 2m (half 0), 2m+1 (half 1)
        for (; (m + 8) * 2 <= degS; m += 8) {
#pragma unroll
            for (int j = 0; j < 8; ++j) {
                int s = __shfl(c, 2 * (m + j) + half, 64);
                float2 f = __half22float2(*((const __half2*)(zs + (size_t)s * 64) + fp));
                if ((j & 3) == 0) { a0.x += f.x; a0.y += f.y; }
                else if ((j & 3) == 1) { a1.x += f.x; a1.y += f.y; }
                else if ((j & 3) == 2) { a2.x += f.x; a2.y += f.y; }
                else { a3.x += f.x; a3.y += f.y; }
            }
        }
        if ((m + 4) * 2 <= degS) {
#pragma unroll
            for (int j = 0; j < 4; ++j) {
                int s = __shfl(c, 2 * (m + j) + half, 64);
                float2 f = __half22float2(*((const __half2*)(zs + (size_t)s * 64) + fp));
                if (j == 0) { a0.x += f.x; a0.y += f.y; }
                else if (j == 1) { a1.x += f.x; a1.y += f.y; }
                else if (j == 2) { a2.x += f.x; a2.y += f.y; }
                else { a3.x += f.x; a3.y += f.y; }
            }
            m += 4;
        }
        if (m * 2 < degS) {
#pragma unroll
            for (int j = 0; j < 4; ++j) {
                int e = 2 * (m + j) + half;
                int ee = (e < degS) ? e : (degS - 1);
                int s = __shfl(c, ee, 64);
                float2 f = __half22float2(*((const __half2*)(zs + (size_t)s * 64) + fp));
                float msk = (e < degS) ? 1.f : 0.f;
                if (j == 0) { a0.x = fmaf(f.x, msk, a0.x); a0.y = fmaf(f.y, msk, a0.y); }
                else if (j == 1) { a1.x = fmaf(f.x, msk, a1.x); a1.y = fmaf(f.y, msk, a1.y); }
                else if (j == 2) { a2.x = fmaf(f.x, msk, a2.x); a2.y = fmaf(f.y, msk, a2.y); }
                else { a3.x = fmaf(f.x, msk, a3.x); a3.y = fmaf(f.y, msk, a3.y); }
            }
        }
        if (deg > 64) {  // rare fallback: direct per-edge col loads for the remainder
            for (int p = beg + 64; p < end; p += 8) {
#pragma unroll
                for (int j = 0; j < 4; ++j) {
                    int e = p + 2 * j + half;
                    int q = (e < end) ? e : (end - 1);
                    int s = col[q];
                    float2 f = __half22float2(*((const __half2*)(zs + (size_t)s * 64) + fp));
                    float msk = (e < end) ? 1.f : 0.f;
                    a0.x = fmaf(f.x, msk, a0.x); a0.y = fmaf(f.y, msk, a0.y);
                }
            }
        }
        float2 a;
        a.x = (a0.x + a1.x) + (a2.x + a3.x);
        a.y = (a0.y + a1.y) + (a2.y + a3.y);
        a.x += __shfl_xor(a.x, 32, 64);
        a.y += __shfl_xor(a.y, 32, 64);
        float iv = idi[v];
        float2 o;
        o.x = fmaf(a.x, iv, bias2.x);
        o.y = fmaf(a.y, iv, bias2.y);
        if (RELU) { o.x = fmaxf(o.x, 0.f); o.y = fmaxf(o.y, 0.f); }

        if (LAST) {
            int gg = gid[v];  // wave-uniform scalar load
            if (gg != curg) {
                if (curg >= 0 && half == 0) {
                    atomicAdd(&out[(size_t)curg * 64 + fp * 2], pacc.x);
                    atomicAdd(&out[(size_t)curg * 64 + fp * 2 + 1], pacc.y);
                }
                curg = gg;
                pacc.x = 0.f; pacc.y = 0.f;
            }
            pacc.x += o.x; pacc.y += o.y;
            float s = o.x * o.x + o.y * o.y;  // both halves identical
#pragma unroll
            for (int off = 32; off > 0; off >>= 1) s += __shfl_xor(s, off, 64);
            if (lane == 0) nacc += sqrtf(0.5f * s);  // halves double-counted
        } else {
            if (half == 0)
                *((__half2*)(xout + (size_t)v * 64) + fp) = __floats2half2_rn(o.x, o.y);
        }

        // rotate pipeline
        beg = nbeg; end = nend; c = cn;
    }

    if (LAST) {
        if (curg >= 0 && half == 0) {
            atomicAdd(&out[(size_t)curg * 64 + fp * 2], pacc.x);
            atomicAdd(&out[(size_t)curg * 64 + fp * 2 + 1], pacc.y);
        }
        if (lane == 0) part[wid] = nacc;
        __syncthreads();
        if (tid == 0) partials[blockIdx.x] = part[0] + part[1] + part[2] + part[3];
    }
}

// ---------------- finish: factor from partials (redundant per block), scale out in place ------
__global__ __launch_bounds__(256) void k_finish(const float* __restrict__ partials,
                                                float* __restrict__ out) {
    __shared__ float sd[256];
    int tid = threadIdx.x;
    float s = 0.f;
    for (int i = tid; i < GATHER_GRID; i += 256) s += partials[i];
    sd[tid] = s;
    __syncthreads();
    for (int off = 128; off > 0; off >>= 1) {
        if (tid < off) sd[tid] += sd[tid + off];
        __syncthreads();
    }
    float factor = 8.0f * (float)N_NODES / sd[0];
    int i = blockIdx.x * 256 + tid;
    if (i < N_GRAPHS * 64) out[i] *= factor;
}

extern "C" void kernel_launch(void* const* d_in, const int* in_sizes, int n_in,
                              void* d_out, int out_size, void* d_ws, size_t ws_size,
                              hipStream_t stream) {
    const float* h    = (const float*)d_in[0];
    const int*   esrc = (const int*)d_in[1];
    const int*   edst = (const int*)d_in[2];
    const int*   gids = (const int*)d_in[3];
    const float* W0 = (const float*)d_in[4];
    const float* b0 = (const float*)d_in[5];
    const float* W1 = (const float*)d_in[6];
    const float* b1 = (const float*)d_in[7];
    const float* W2 = (const float*)d_in[8];
    const float* b2 = (const float*)d_in[9];
    float* out = (float*)d_out;

    char* wsp = (char*)d_ws;
    size_t off = 0;
    auto alloc = [&](size_t bytes) -> void* {
        void* p = wsp + off;
        off += (bytes + 255) & ~(size_t)255;
        return p;
    };
    // cursors: [0,16) sup-dst, [16,32) sup-src, [32,423) sub-dst, [423,814) sub-src
    int*   cursors    = (int*)alloc(814 * 4);
    float* odi        = (float*)alloc((size_t)N_NODES * 4);
    float* idi        = (float*)alloc((size_t)N_NODES * 4);
    int*   rowbeg     = (int*)alloc((size_t)N_NODES * 4);
    int*   rowend     = (int*)alloc((size_t)N_NODES * 4);
    float* partials   = (float*)alloc((size_t)GATHER_GRID * 4);
    int*   col        = (int*)alloc((size_t)NB * CAP * 4);          // 8.0 MB, fixed-stride
    __half* zsb       = (__half*)alloc((size_t)N_NODES * 64 * 2);   // 12.8 MB
    __half* xh        = (__half*)alloc((size_t)N_NODES * 64 * 2);   // 12.8 MB
    unsigned*       sup_dst  = (unsigned*)alloc((size_t)NSUP * CAP_S * 4);        // 6.82 MB
    unsigned short* sup_src  = (unsigned short*)alloc((size_t)NSUP * CAP_S * 2);  // 3.41 MB
    unsigned*       part_dst = (unsigned*)alloc((size_t)NB * CAP * 4);            // 8.00 MB
    unsigned char*  part_src = (unsigned char*)alloc((size_t)NB * CAP);           // 2.00 MB

    int* scur_dst = cursors;
    int* scur_src = cursors + 16;
    int* gcur_dst = cursors + 32;
    int* gcur_src = cursors + 32 + NB;

    k_zero2<<<(N_GRAPHS * 64 + 255) / 256, 256, 0, stream>>>(cursors, 814, (int*)out, N_GRAPHS * 64);

    // CSR build: two-level radix partition (16 supers -> 25 subs each), then per-bucket CSR/count
    k_passA<<<NCH_A, 256, 0, stream>>>(esrc, edst, scur_dst, scur_src, sup_dst, sup_src);
    k_passB<<<2 * NSUP * NCHB, 256, 0, stream>>>(sup_dst, sup_src, scur_dst, scur_src,
                                                 gcur_dst, gcur_src, part_dst, part_src);
    k_csr_count<<<2 * NB, 256, 0, stream>>>(part_dst, part_src, gcur_dst, gcur_src,
                                            rowbeg, rowend, idi, odi, col);

    // layer 0: z = h@W0 (MFMA, odi-scaled fp16) -> gather
    k_gemm_mfma<1><<<GEMM_GRID, 256, 0, stream>>>(h, W0, odi, zsb);
    k_gather<1, 0><<<GATHER_GRID, 256, 0, stream>>>(zsb, rowbeg, rowend, col, idi, b0, xh,
                                                    nullptr, nullptr, nullptr);
    // layer 1
    k_gemm_mfma<0><<<GEMM_GRID, 256, 0, stream>>>(xh, W1, odi, zsb);
    k_gather<1, 0><<<GATHER_GRID, 256, 0, stream>>>(zsb, rowbeg, rowend, col, idi, b1, xh,
                                                    nullptr, nullptr, nullptr);
    // layer 2 (last: fused unscaled sum-pool + norm partials; no xh write)
    k_gemm_mfma<0><<<GEMM_GRID, 256, 0, stream>>>(xh, W2, odi, zsb);
    k_gather<0, 1><<<GATHER_GRID, 256, 0, stream>>>(zsb, rowbeg, rowend, col, idi, b2, nullptr,
                                                    gids, out, partials);

    // factor + in-place scale of pooled output
    k_finish<<<(N_GRAPHS * 64 + 255) / 256, 256, 0, stream>>>(partials, out);
}

// Round 14
// 194.053 us; speedup vs baseline: 1.0188x; 1.0188x over previous
//
#include <hip/hip_runtime.h>
#include <hip/hip_fp16.h>

#define N_NODES 100000
#define N_EDGES 1600000
#define N_GRAPHS 2000
#define HID 64
#define NB 391          // final buckets of 256 nodes
#define CAP 5120        // per-bucket capacity (mean 4096; +16 sigma)
#define NSUP 16         // super-buckets of SUPW nodes
#define SUPW 6400       // 25 * 256
#define CAP_S 106496    // per-super capacity (mean 102400, +13 sigma), = 26*4096
#define CH_A 2048
#define NCH_A ((N_EDGES + CH_A - 1) / CH_A)   // 782
#define BCH 4096
#define NCHB 26         // CAP_S / BCH
#define GATHER_GRID 2048
#define NPW 13          // nodes per wave: 2048*4*13 = 106496 >= N_NODES
#define GEMM_GRID 512
#define N_TILE16 (N_NODES / 16)  // 6250 (exact)

typedef _Float16 half8 __attribute__((ext_vector_type(8)));
typedef float f32x4 __attribute__((ext_vector_type(4)));

// ---------------- utility: zero two ranges in one launch ----------------
__global__ __launch_bounds__(256) void k_zero2(int* __restrict__ p1, int n1,
                                               int* __restrict__ p2, int n2) {
    int i = blockIdx.x * 256 + threadIdx.x;
    if (i < n1) p1[i] = 0;
    if (i < n2) p2[i] = 0;
}

// ---------------- pass A: 16-way super-bucket split (dst u32 entries, src u16 entries) --------
__global__ __launch_bounds__(256) void k_passA(const int* __restrict__ src, const int* __restrict__ dst,
                                               int* __restrict__ scur_dst, int* __restrict__ scur_src,
                                               unsigned* __restrict__ sup_dst,
                                               unsigned short* __restrict__ sup_src) {
    __shared__ unsigned stD[CH_A];
    __shared__ unsigned short stS[CH_A];
    __shared__ unsigned char binD[CH_A];
    __shared__ unsigned char binS[CH_A];
    __shared__ int lcntD[NSUP], lexD[NSUP], lofD[NSUP], runD[NSUP];
    __shared__ int lcntS[NSUP], lexS[NSUP], lofS[NSUP], runS[NSUP];
    int tid = threadIdx.x;
    int e0 = blockIdx.x * CH_A;
    int n = min(CH_A, N_EDGES - e0);
    if (tid < NSUP) { lcntD[tid] = 0; lcntS[tid] = 0; }
    __syncthreads();
    int sv[8], dv[8];
#pragma unroll
    for (int k = 0; k < 8; ++k) {
        int i = k * 256 + tid;
        if (i < n) { sv[k] = src[e0 + i]; dv[k] = dst[e0 + i]; }
        else dv[k] = -1;
    }
#pragma unroll
    for (int k = 0; k < 8; ++k)
        if (dv[k] >= 0) {
            atomicAdd(&lcntD[dv[k] / SUPW], 1);
            atomicAdd(&lcntS[sv[k] / SUPW], 1);
        }
    __syncthreads();
    if (tid == 0)  { int a = 0; for (int i = 0; i < NSUP; ++i) { lexD[i] = a; lofD[i] = a; a += lcntD[i]; } }
    if (tid == 64) { int a = 0; for (int i = 0; i < NSUP; ++i) { lexS[i] = a; lofS[i] = a; a += lcntS[i]; } }
    __syncthreads();
#pragma unroll
    for (int k = 0; k < 8; ++k)
        if (dv[k] >= 0) {
            int d = dv[k], s = sv[k];
            int bD = d / SUPW;
            int pD = atomicAdd(&lofD[bD], 1);
            stD[pD] = ((unsigned)(d - bD * SUPW) << 17) | (unsigned)s;
            binD[pD] = (unsigned char)bD;
            int bS = s / SUPW;
            int pS = atomicAdd(&lofS[bS], 1);
            stS[pS] = (unsigned short)(s - bS * SUPW);
            binS[pS] = (unsigned char)bS;
        }
    __syncthreads();
    if (tid < NSUP) runD[tid] = lcntD[tid] ? atomicAdd(&scur_dst[tid], lcntD[tid]) : 0;
    if (tid >= 128 && tid < 128 + NSUP) {
        int b = tid - 128;
        runS[b] = lcntS[b] ? atomicAdd(&scur_src[b], lcntS[b]) : 0;
    }
    __syncthreads();
    for (int i = tid; i < n; i += 256) {
        int b = binD[i];
        int pos = runD[b] + (i - lexD[b]);
        if (pos < CAP_S) sup_dst[(size_t)b * CAP_S + pos] = stD[i];
    }
    for (int i = tid; i < n; i += 256) {
        int b = binS[i];
        int pos = runS[b] + (i - lexS[b]);
        if (pos < CAP_S) sup_src[(size_t)b * CAP_S + pos] = stS[i];
    }
}

// ---------------- pass B: refine each super-bucket into its 25 sub-buckets ----------------
__global__ __launch_bounds__(256) void k_passB(const unsigned* __restrict__ sup_dst,
                                               const unsigned short* __restrict__ sup_src,
                                               const int* __restrict__ scur_dst,
                                               const int* __restrict__ scur_src,
                                               int* __restrict__ gcur_dst, int* __restrict__ gcur_src,
                                               unsigned* __restrict__ part_dst,
                                               unsigned char* __restrict__ part_src) {
    __shared__ unsigned st[BCH];
    __shared__ unsigned char bin[BCH];
    __shared__ int lcnt[25], lex[25], lof[25], run[25];
    int tid = threadIdx.x;
    int isSrc = blockIdx.x >= NSUP * NCHB;
    int bx = isSrc ? blockIdx.x - NSUP * NCHB : blockIdx.x;
    int sb = bx / NCHB, ch = bx % NCHB;
    int total = isSrc ? scur_src[sb] : scur_dst[sb];
    total = min(total, CAP_S);
    int o0 = ch * BCH;
    int n = min(BCH, total - o0);
    if (n <= 0) return;
    int bg0 = sb * 25;
    if (tid < 25) lcnt[tid] = 0;
    __syncthreads();

    if (!isSrc) {
        unsigned ev[16];
        int bb[16];
#pragma unroll
        for (int k = 0; k < 16; ++k) {
            int i = k * 256 + tid;
            if (i < n) {
                unsigned e = sup_dst[(size_t)sb * CAP_S + o0 + i];
                ev[k] = e;
                bb[k] = (int)(e >> 25);
                atomicAdd(&lcnt[bb[k]], 1);
            } else bb[k] = -1;
        }
        __syncthreads();
        if (tid == 0) { int a = 0; for (int i = 0; i < 25; ++i) { lex[i] = a; lof[i] = a; a += lcnt[i]; } }
        __syncthreads();
#pragma unroll
        for (int k = 0; k < 16; ++k)
            if (bb[k] >= 0) {
                unsigned e = ev[k];
                unsigned s = e & 0x1FFFFu;
                unsigned low = (e >> 17) & 255u;
                int p = atomicAdd(&lof[bb[k]], 1);
                st[p] = (s << 8) | low;
                bin[p] = (unsigned char)bb[k];
            }
        __syncthreads();
        if (tid < 25) run[tid] = lcnt[tid] ? atomicAdd(&gcur_dst[bg0 + tid], lcnt[tid]) : 0;
        __syncthreads();
        for (int i = tid; i < n; i += 256) {
            int b = bin[i];
            int pos = run[b] + (i - lex[b]);
            if (pos < CAP) part_dst[(size_t)(bg0 + b) * CAP + pos] = st[i];
        }
    } else {
        unsigned char* st8 = (unsigned char*)st;
        int rv[16];
        int bb[16];
#pragma unroll
        for (int k = 0; k < 16; ++k) {
            int i = k * 256 + tid;
            if (i < n) {
                int r = (int)sup_src[(size_t)sb * CAP_S + o0 + i];
                rv[k] = r;
                bb[k] = r >> 8;
                atomicAdd(&lcnt[bb[k]], 1);
            } else bb[k] = -1;
        }
        __syncthreads();
        if (tid == 0) { int a = 0; for (int i = 0; i < 25; ++i) { lex[i] = a; lof[i] = a; a += lcnt[i]; } }
        __syncthreads();
#pragma unroll
        for (int k = 0; k < 16; ++k)
            if (bb[k] >= 0) {
                int p = atomicAdd(&lof[bb[k]], 1);
                st8[p] = (unsigned char)(rv[k] & 255);
                bin[p] = (unsigned char)bb[k];
            }
        __syncthreads();
        if (tid < 25) run[tid] = lcnt[tid] ? atomicAdd(&gcur_src[bg0 + tid], lcnt[tid]) : 0;
        __syncthreads();
        for (int i = tid; i < n; i += 256) {
            int b = bin[i];
            int pos = run[b] + (i - lex[b]);
            if (pos < CAP) part_src[(size_t)(bg0 + b) * CAP + pos] = st8[i];
        }
    }
}

// ---------------- merged: blocks [0,NB) build dst CSR; [NB,2NB) count out-deg -> odi ----------
__global__ __launch_bounds__(256) void k_csr_count(const unsigned* __restrict__ part_dst,
                                                   const unsigned char* __restrict__ part_src,
                                                   const int* __restrict__ gcur_dst,
                                                   const int* __restrict__ gcur_src,
                                                   int* __restrict__ rowbeg, int* __restrict__ rowend,
                                                   float* __restrict__ idi, float* __restrict__ odi,
                                                   int* __restrict__ col) {
    __shared__ int cnt[256];
    __shared__ int cur[256];
    __shared__ int wsum[4];
    int tid = threadIdx.x;
    if (blockIdx.x >= NB) {
        int b = blockIdx.x - NB;
        int nE = min(gcur_src[b], CAP);
        const unsigned char* pb = part_src + (size_t)b * CAP;
        cnt[tid] = 0;
        __syncthreads();
        for (int i = tid; i < nE; i += 256) atomicAdd(&cnt[pb[i]], 1);
        __syncthreads();
        int v = b * 256 + tid;
        if (v < N_NODES) odi[v] = rsqrtf((float)max(cnt[tid], 1));
        return;
    }
    int b = blockIdx.x;
    int base = b * CAP;
    int nE = min(gcur_dst[b], CAP);
    const unsigned* pb = part_dst + (size_t)b * CAP;
    cnt[tid] = 0;
    __syncthreads();
    for (int i = tid; i < nE; i += 256) atomicAdd(&cnt[pb[i] & 255], 1);
    __syncthreads();
    int c = cnt[tid];
    int incl = c;
#pragma unroll
    for (int off = 1; off < 64; off <<= 1) {
        int t = __shfl_up(incl, off, 64);
        if ((tid & 63) >= off) incl += t;
    }
    if ((tid & 63) == 63) wsum[tid >> 6] = incl;
    __syncthreads();
    int add = 0;
    for (int w = 0; w < (tid >> 6); ++w) add += wsum[w];
    incl += add;
    int excl = incl - c;
    int v = b * 256 + tid;
    if (v < N_NODES) {
        rowbeg[v] = base + excl;
        rowend[v] = base + incl;
        idi[v] = rsqrtf((float)max(c, 1));
    }
    cur[tid] = excl;
    __syncthreads();
    for (int i = tid; i < nE; i += 256) {
        unsigned e = pb[i];
        int p = atomicAdd(&cur[e & 255], 1);
        col[base + p] = (int)(e >> 8);
    }
}

// ---------------- dense GEMM via MFMA: zs[v] = (x[v] @ W) * odi[v]  (fp16 out) ----------------
template <int F32IN>
__global__ __launch_bounds__(256) void k_gemm_mfma(const void* __restrict__ inv,
                                                   const float* __restrict__ W,
                                                   const float* __restrict__ odi,
                                                   __half* __restrict__ zs) {
    __shared__ _Float16 Wt[64 * 64];  // Wt[j][k] = W[k][j]
    int tid = threadIdx.x;
    for (int i = tid; i < 4096; i += 256) {
        int k = i >> 6, j = i & 63;
        Wt[j * 64 + k] = (_Float16)W[i];
    }
    __syncthreads();

    int lane = tid & 63;
    int wid = tid >> 6;
    int lrow = lane & 15;
    int lgrp = lane >> 4;

    half8 Bf[4][2];
#pragma unroll
    for (int nt = 0; nt < 4; ++nt)
#pragma unroll
        for (int kh = 0; kh < 2; ++kh)
            Bf[nt][kh] = *(half8*)&Wt[(nt * 16 + lrow) * 64 + kh * 32 + lgrp * 8];

    for (int t = blockIdx.x * 4 + wid; t < N_TILE16; t += GEMM_GRID * 4) {
        int v0 = t * 16;
        half8 a0, a1;
        if (F32IN) {
            const float* A = (const float*)inv + (size_t)(v0 + lrow) * 64 + lgrp * 8;
            float4 f0 = *(const float4*)A;
            float4 f1 = *(const float4*)(A + 4);
            float4 g0 = *(const float4*)(A + 32);
            float4 g1 = *(const float4*)(A + 36);
            a0[0] = (_Float16)f0.x; a0[1] = (_Float16)f0.y; a0[2] = (_Float16)f0.z; a0[3] = (_Float16)f0.w;
            a0[4] = (_Float16)f1.x; a0[5] = (_Float16)f1.y; a0[6] = (_Float16)f1.z; a0[7] = (_Float16)f1.w;
            a1[0] = (_Float16)g0.x; a1[1] = (_Float16)g0.y; a1[2] = (_Float16)g0.z; a1[3] = (_Float16)g0.w;
            a1[4] = (_Float16)g1.x; a1[5] = (_Float16)g1.y; a1[6] = (_Float16)g1.z; a1[7] = (_Float16)g1.w;
        } else {
            const _Float16* A = (const _Float16*)inv + (size_t)(v0 + lrow) * 64 + lgrp * 8;
            a0 = *(const half8*)A;
            a1 = *(const half8*)(A + 32);
        }
        f32x4 acc[4];
#pragma unroll
        for (int nt = 0; nt < 4; ++nt) { acc[nt] = (f32x4)0.f; }
#pragma unroll
        for (int nt = 0; nt < 4; ++nt) {
            acc[nt] = __builtin_amdgcn_mfma_f32_16x16x32_f16(a0, Bf[nt][0], acc[nt], 0, 0, 0);
            acc[nt] = __builtin_amdgcn_mfma_f32_16x16x32_f16(a1, Bf[nt][1], acc[nt], 0, 0, 0);
        }
#pragma unroll
        for (int r = 0; r < 4; ++r) {
            int node = v0 + lgrp * 4 + r;
            float w = odi[node];
#pragma unroll
            for (int nt = 0; nt < 4; ++nt)
                zs[(size_t)node * 64 + nt * 16 + lrow] = __float2half_rn(acc[nt][r] * w);
        }
    }
}

// ---------------- gather v4: per-wave consecutive nodes; LAST fuses unscaled sum-pool -------
// lane = (edge-parity half, feature-pair fp). One coalesced col load per node + shfl srcs.
template <int RELU, int LAST>
__global__ __launch_bounds__(256) void k_gather(const __half* __restrict__ zs, const int* __restrict__ rowbeg,
                                                const int* __restrict__ rowend, const int* __restrict__ col,
                                                const float* __restrict__ idi, const float* __restrict__ b,
                                                __half* __restrict__ xout, const int* __restrict__ gid,
                                                float* __restrict__ out, float* __restrict__ partials) {
    __shared__ float part[4];
    int tid = threadIdx.x;
    int lane = tid & 63;
    int wid = tid >> 6;
    int half = lane >> 5;   // 0: even edge slot, 1: odd edge slot
    int fp = lane & 31;     // feature-pair
    float2 bias2 = *(const float2*)&b[fp * 2];
    float nacc = 0.f;
    float2 pacc = {0.f, 0.f};
    int curg = -1;

    int w = __builtin_amdgcn_readfirstlane(blockIdx.x * 4 + wid);
    int v0 = w * NPW;
    int vend = min(v0 + NPW, N_NODES);

    for (int v = v0; v < vend; ++v) {
        int beg = rowbeg[v], end = rowend[v];
        int deg = end - beg;
        int degS = min(deg, 64);  // edges served by the shfl path
        int c = col[beg + min(lane, max(degS - 1, 0))];  // one coalesced load
        float2 a0 = {0.f, 0.f}, a1 = {0.f, 0.f}, a2 = {0.f, 0.f}, a3 = {0.f, 0.f};
        int m = 0;  // pair-slot index; slot m covers edges 2m (half 0), 2m+1 (half 1)
        for (; (m + 8) * 2 <= degS; m += 8) {
#pragma unroll
            for (int j = 0; j < 8; ++j) {
                int s = __shfl(c, 2 * (m + j) + half, 64);
                float2 f = __half22float2(*((const __half2*)(zs + (size_t)s * 64) + fp));
                if ((j & 3) == 0) { a0.x += f.x; a0.y += f.y; }
                else if ((j & 3) == 1) { a1.x += f.x; a1.y += f.y; }
                else if ((j & 3) == 2) { a2.x += f.x; a2.y += f.y; }
                else { a3.x += f.x; a3.y += f.y; }
            }
        }
        if ((m + 4) * 2 <= degS) {
#pragma unroll
            for (int j = 0; j < 4; ++j) {
                int s = __shfl(c, 2 * (m + j) + half, 64);
                float2 f = __half22float2(*((const __half2*)(zs + (size_t)s * 64) + fp));
                if (j == 0) { a0.x += f.x; a0.y += f.y; }
                else if (j == 1) { a1.x += f.x; a1.y += f.y; }
                else if (j == 2) { a2.x += f.x; a2.y += f.y; }
                else { a3.x += f.x; a3.y += f.y; }
            }
            m += 4;
        }
        if (m * 2 < degS) {
#pragma unroll
            for (int j = 0; j < 4; ++j) {
                int e = 2 * (m + j) + half;
                int ee = (e < degS) ? e : (degS - 1);
                int s = __shfl(c, ee, 64);
                float2 f = __half22float2(*((const __half2*)(zs + (size_t)s * 64) + fp));
                float msk = (e < degS) ? 1.f : 0.f;
                if (j == 0) { a0.x = fmaf(f.x, msk, a0.x); a0.y = fmaf(f.y, msk, a0.y); }
                else if (j == 1) { a1.x = fmaf(f.x, msk, a1.x); a1.y = fmaf(f.y, msk, a1.y); }
                else if (j == 2) { a2.x = fmaf(f.x, msk, a2.x); a2.y = fmaf(f.y, msk, a2.y); }
                else { a3.x = fmaf(f.x, msk, a3.x); a3.y = fmaf(f.y, msk, a3.y); }
            }
        }
        if (deg > 64) {  // rare fallback: direct per-edge col loads for the remainder
            for (int p = beg + 64; p < end; p += 8) {
#pragma unroll
                for (int j = 0; j < 4; ++j) {
                    int e = p + 2 * j + half;
                    int q = (e < end) ? e : (end - 1);
                    int s = col[q];
                    float2 f = __half22float2(*((const __half2*)(zs + (size_t)s * 64) + fp));
                    float msk = (e < end) ? 1.f : 0.f;
                    a0.x = fmaf(f.x, msk, a0.x); a0.y = fmaf(f.y, msk, a0.y);
                }
            }
        }
        float2 a;
        a.x = (a0.x + a1.x) + (a2.x + a3.x);
        a.y = (a0.y + a1.y) + (a2.y + a3.y);
        a.x += __shfl_xor(a.x, 32, 64);
        a.y += __shfl_xor(a.y, 32, 64);
        float iv = idi[v];
        float2 o;
        o.x = fmaf(a.x, iv, bias2.x);
        o.y = fmaf(a.y, iv, bias2.y);
        if (RELU) { o.x = fmaxf(o.x, 0.f); o.y = fmaxf(o.y, 0.f); }

        if (LAST) {
            int gg = gid[v];  // wave-uniform scalar load
            if (gg != curg) {
                if (curg >= 0 && half == 0) {
                    atomicAdd(&out[(size_t)curg * 64 + fp * 2], pacc.x);
                    atomicAdd(&out[(size_t)curg * 64 + fp * 2 + 1], pacc.y);
                }
                curg = gg;
                pacc.x = 0.f; pacc.y = 0.f;
            }
            pacc.x += o.x; pacc.y += o.y;
            float s = o.x * o.x + o.y * o.y;  // both halves identical
#pragma unroll
            for (int off = 32; off > 0; off >>= 1) s += __shfl_xor(s, off, 64);
            if (lane == 0) nacc += sqrtf(0.5f * s);  // halves double-counted
        } else {
            if (half == 0)
                *((__half2*)(xout + (size_t)v * 64) + fp) = __floats2half2_rn(o.x, o.y);
        }
    }

    if (LAST) {
        if (curg >= 0 && half == 0) {
            atomicAdd(&out[(size_t)curg * 64 + fp * 2], pacc.x);
            atomicAdd(&out[(size_t)curg * 64 + fp * 2 + 1], pacc.y);
        }
        if (lane == 0) part[wid] = nacc;
        __syncthreads();
        if (tid == 0) partials[blockIdx.x] = part[0] + part[1] + part[2] + part[3];
    }
}

// ---------------- finish: factor from partials (redundant per block), scale out in place ------
__global__ __launch_bounds__(256) void k_finish(const float* __restrict__ partials,
                                                float* __restrict__ out) {
    __shared__ float sd[256];
    int tid = threadIdx.x;
    float s = 0.f;
    for (int i = tid; i < GATHER_GRID; i += 256) s += partials[i];
    sd[tid] = s;
    __syncthreads();
    for (int off = 128; off > 0; off >>= 1) {
        if (tid < off) sd[tid] += sd[tid + off];
        __syncthreads();
    }
    float factor = 8.0f * (float)N_NODES / sd[0];
    int i = blockIdx.x * 256 + tid;
    if (i < N_GRAPHS * 64) out[i] *= factor;
}

extern "C" void kernel_launch(void* const* d_in, const int* in_sizes, int n_in,
                              void* d_out, int out_size, void* d_ws, size_t ws_size,
                              hipStream_t stream) {
    const float* h    = (const float*)d_in[0];
    const int*   esrc = (const int*)d_in[1];
    const int*   edst = (const int*)d_in[2];
    const int*   gids = (const int*)d_in[3];
    const float* W0 = (const float*)d_in[4];
    const float* b0 = (const float*)d_in[5];
    const float* W1 = (const float*)d_in[6];
    const float* b1 = (const float*)d_in[7];
    const float* W2 = (const float*)d_in[8];
    const float* b2 = (const float*)d_in[9];
    float* out = (float*)d_out;

    char* wsp = (char*)d_ws;
    size_t off = 0;
    auto alloc = [&](size_t bytes) -> void* {
        void* p = wsp + off;
        off += (bytes + 255) & ~(size_t)255;
        return p;
    };
    // cursors: [0,16) sup-dst, [16,32) sup-src, [32,423) sub-dst, [423,814) sub-src
    int*   cursors    = (int*)alloc(814 * 4);
    float* odi        = (float*)alloc((size_t)N_NODES * 4);
    float* idi        = (float*)alloc((size_t)N_NODES * 4);
    int*   rowbeg     = (int*)alloc((size_t)N_NODES * 4);
    int*   rowend     = (int*)alloc((size_t)N_NODES * 4);
    float* partials   = (float*)alloc((size_t)GATHER_GRID * 4);
    int*   col        = (int*)alloc((size_t)NB * CAP * 4);          // 8.0 MB, fixed-stride
    __half* zsb       = (__half*)alloc((size_t)N_NODES * 64 * 2);   // 12.8 MB
    __half* xh        = (__half*)alloc((size_t)N_NODES * 64 * 2);   // 12.8 MB
    unsigned*       sup_dst  = (unsigned*)alloc((size_t)NSUP * CAP_S * 4);        // 6.82 MB
    unsigned short* sup_src  = (unsigned short*)alloc((size_t)NSUP * CAP_S * 2);  // 3.41 MB
    unsigned*       part_dst = (unsigned*)alloc((size_t)NB * CAP * 4);            // 8.00 MB
    unsigned char*  part_src = (unsigned char*)alloc((size_t)NB * CAP);           // 2.00 MB

    int* scur_dst = cursors;
    int* scur_src = cursors + 16;
    int* gcur_dst = cursors + 32;
    int* gcur_src = cursors + 32 + NB;

    k_zero2<<<(N_GRAPHS * 64 + 255) / 256, 256, 0, stream>>>(cursors, 814, (int*)out, N_GRAPHS * 64);

    // CSR build: two-level radix partition (16 supers -> 25 subs each), then per-bucket CSR/count
    k_passA<<<NCH_A, 256, 0, stream>>>(esrc, edst, scur_dst, scur_src, sup_dst, sup_src);
    k_passB<<<2 * NSUP * NCHB, 256, 0, stream>>>(sup_dst, sup_src, scur_dst, scur_src,
                                                 gcur_dst, gcur_src, part_dst, part_src);
    k_csr_count<<<2 * NB, 256, 0, stream>>>(part_dst, part_src, gcur_dst, gcur_src,
                                            rowbeg, rowend, idi, odi, col);

    // layer 0: z = h@W0 (MFMA, odi-scaled fp16) -> gather
    k_gemm_mfma<1><<<GEMM_GRID, 256, 0, stream>>>(h, W0, odi, zsb);
    k_gather<1, 0><<<GATHER_GRID, 256, 0, stream>>>(zsb, rowbeg, rowend, col, idi, b0, xh,
                                                    nullptr, nullptr, nullptr);
    // layer 1
    k_gemm_mfma<0><<<GEMM_GRID, 256, 0, stream>>>(xh, W1, odi, zsb);
    k_gather<1, 0><<<GATHER_GRID, 256, 0, stream>>>(zsb, rowbeg, rowend, col, idi, b1, xh,
                                                    nullptr, nullptr, nullptr);
    // layer 2 (last: fused unscaled sum-pool + norm partials; no xh write)
    k_gemm_mfma<0><<<GEMM_GRID, 256, 0, stream>>>(xh, W2, odi, zsb);
    k_gather<0, 1><<<GATHER_GRID, 256, 0, stream>>>(zsb, rowbeg, rowend, col, idi, b2, nullptr,
                                                    gids, out, partials);

    // factor + in-place scale of pooled output
    k_finish<<<(N_GRAPHS * 64 + 255) / 256, 256, 0, stream>>>(partials, out);
}